// Round 1
// baseline (838.461 us; speedup 1.0000x reference)
//
#include <hip/hip_runtime.h>
#include <cmath>

#define T_SIZE (1u << 19)

typedef _Float16 h8 __attribute__((ext_vector_type(8)));
typedef float f4 __attribute__((ext_vector_type(4)));

struct Levels {
    float scale[16];
    int   res[16];
    unsigned dense_mask;
};

// softplus(10z)/10 via hardware exp2/log2 (v_exp_f32 / v_log_f32)
__device__ __forceinline__ float softplus10(float z) {
    float y = z * 10.0f;
    float t = __builtin_amdgcn_exp2f(y * 1.4426950408889634f);       // e^y
    float sp = __builtin_amdgcn_logf(1.0f + t) * 0.069314718055994531f; // ln(1+e^y)/10
    return (y > 20.0f) ? z : sp;
}

// ---------------- Kernel A: hash-grid encode -> f16 [N][32] ----------------
__global__ __launch_bounds__(256) void encode_kernel(
    const float* __restrict__ xs, const float* __restrict__ table,
    _Float16* __restrict__ enc, Levels lv, int N)
{
    int i = blockIdx.x * 256 + threadIdx.x;
    if (i >= N) return;
    float px = xs[3 * i + 0], py = xs[3 * i + 1], pz = xs[3 * i + 2];

    h8 pk[4];
#pragma unroll
    for (int l = 0; l < 16; ++l) {
        float s = lv.scale[l];
        int res = lv.res[l];
        float fx = px * s + 0.5f, fy = py * s + 0.5f, fz = pz * s + 0.5f;
        float gx = floorf(fx), gy = floorf(fy), gz = floorf(fz);
        float wx = fx - gx, wy = fy - gy, wz = fz - gz;
        int cx = (int)gx, cy = (int)gy, cz = (int)gz;

        unsigned idx[8];
        if ((lv.dense_mask >> l) & 1u) {
            int r1 = res - 1;
            int x0 = min(cx, r1), x1 = min(cx + 1, r1);
            int y0 = min(cy, r1), y1 = min(cy + 1, r1);
            int z0 = min(cz, r1), z1 = min(cz + 1, r1);
            int yr0 = y0 * res, yr1 = y1 * res;
            int rr = res * res;
            int zr0 = z0 * rr, zr1 = z1 * rr;
            // corner c: xo=c>>2, yo=(c>>1)&1, zo=c&1  (matches meshgrid 'ij' order)
            idx[0] = x0 + yr0 + zr0;
            idx[1] = x0 + yr0 + zr1;
            idx[2] = x0 + yr1 + zr0;
            idx[3] = x0 + yr1 + zr1;
            idx[4] = x1 + yr0 + zr0;
            idx[5] = x1 + yr0 + zr1;
            idx[6] = x1 + yr1 + zr0;
            idx[7] = x1 + yr1 + zr1;
        } else {
            unsigned hx0 = (unsigned)cx, hx1 = (unsigned)(cx + 1);
            unsigned hy0 = (unsigned)cy * 2654435761u, hy1 = (unsigned)(cy + 1) * 2654435761u;
            unsigned hz0 = (unsigned)cz * 805459861u,  hz1 = (unsigned)(cz + 1) * 805459861u;
            idx[0] = (hx0 ^ hy0 ^ hz0) & (T_SIZE - 1);
            idx[1] = (hx0 ^ hy0 ^ hz1) & (T_SIZE - 1);
            idx[2] = (hx0 ^ hy1 ^ hz0) & (T_SIZE - 1);
            idx[3] = (hx0 ^ hy1 ^ hz1) & (T_SIZE - 1);
            idx[4] = (hx1 ^ hy0 ^ hz0) & (T_SIZE - 1);
            idx[5] = (hx1 ^ hy0 ^ hz1) & (T_SIZE - 1);
            idx[6] = (hx1 ^ hy1 ^ hz0) & (T_SIZE - 1);
            idx[7] = (hx1 ^ hy1 ^ hz1) & (T_SIZE - 1);
        }

        const float2* tl = ((const float2*)table) + (size_t)l * T_SIZE;
        float2 v[8];
#pragma unroll
        for (int c = 0; c < 8; ++c) v[c] = tl[idx[c]];

        float wx0 = 1.f - wx, wy0 = 1.f - wy, wz0 = 1.f - wz;
        float wxy00 = wx0 * wy0, wxy01 = wx0 * wy, wxy10 = wx * wy0, wxy11 = wx * wy;
        float f0 = 0.f, f1 = 0.f, wc;
        wc = wxy00 * wz0; f0 += wc * v[0].x; f1 += wc * v[0].y;
        wc = wxy00 * wz;  f0 += wc * v[1].x; f1 += wc * v[1].y;
        wc = wxy01 * wz0; f0 += wc * v[2].x; f1 += wc * v[2].y;
        wc = wxy01 * wz;  f0 += wc * v[3].x; f1 += wc * v[3].y;
        wc = wxy10 * wz0; f0 += wc * v[4].x; f1 += wc * v[4].y;
        wc = wxy10 * wz;  f0 += wc * v[5].x; f1 += wc * v[5].y;
        wc = wxy11 * wz0; f0 += wc * v[6].x; f1 += wc * v[6].y;
        wc = wxy11 * wz;  f0 += wc * v[7].x; f1 += wc * v[7].y;

        pk[l >> 2][(l & 3) * 2]     = (_Float16)f0;
        pk[l >> 2][(l & 3) * 2 + 1] = (_Float16)f1;
    }

    h8* dst = (h8*)(enc + (size_t)i * 32);
    dst[0] = pk[0]; dst[1] = pk[1]; dst[2] = pk[2]; dst[3] = pk[3];
}

// ---------------- Kernel B: fused MLP via f16 MFMA ----------------
// Block: 256 thr (4 waves), 256 points. Wave handles 64 pts (4 tiles of 16).
// A-layout: A[m=lane&15][k=quad*8+j]; D-layout: D[row=quad*4+r][col=lane&15].
__global__ __launch_bounds__(256) void mlp_kernel(
    const _Float16* __restrict__ enc,
    const float* __restrict__ w1, const float* __restrict__ w2,
    const float* __restrict__ w3, const float* __restrict__ w4,
    float* __restrict__ out)
{
    constexpr int W1R = 40;  // 32+8 halves: 80B rows -> 20-bank rotation, <=2-way
    constexpr int W2R = 72;  // 64+8 halves: 144B rows -> 4-bank rotation, <=2-way
    constexpr int AR  = 72;  // activation row stride (16B-aligned, conflict-light)
    __shared__ _Float16 sW1[64 * W1R];
    __shared__ _Float16 sW2[64 * W2R];
    __shared__ _Float16 sW3[64 * W2R];
    __shared__ float    sW4[64];
    __shared__ _Float16 sAct[256 * AR];   // [local_pt][64]

    const int tid = threadIdx.x;
    for (int i = tid; i < 64 * 32; i += 256) sW1[(i >> 5) * W1R + (i & 31)] = (_Float16)w1[i];
    for (int i = tid; i < 64 * 64; i += 256) sW2[(i >> 6) * W2R + (i & 63)] = (_Float16)w2[i];
    for (int i = tid; i < 64 * 64; i += 256) sW3[(i >> 6) * W2R + (i & 63)] = (_Float16)w3[i];
    if (tid < 64) sW4[tid] = w4[tid];
    __syncthreads();

    const int wave = tid >> 6;
    const int lane = tid & 63;
    const int lrow = lane & 15;
    const int quad = lane >> 4;
    const int blockPt = blockIdx.x * 256;
    const int waveRow = wave * 64;
    const f4 zero = {0.f, 0.f, 0.f, 0.f};

    // ---- Layer 1: enc(global, [N][32] f16) @ w1^T ----
    h8 b1[4];
#pragma unroll
    for (int tn = 0; tn < 4; ++tn)
        b1[tn] = *(const h8*)&sW1[(lrow + 16 * tn) * W1R + quad * 8];

#pragma unroll
    for (int t = 0; t < 4; ++t) {
        const size_t rowg = (size_t)(blockPt + waveRow + t * 16 + lrow);
        h8 a = *(const h8*)(enc + rowg * 32 + quad * 8);  // coalesced A-frag
#pragma unroll
        for (int tn = 0; tn < 4; ++tn) {
            f4 acc = __builtin_amdgcn_mfma_f32_16x16x32_f16(a, b1[tn], zero, 0, 0, 0);
#pragma unroll
            for (int r = 0; r < 4; ++r) {
                int prow = waveRow + t * 16 + quad * 4 + r;
                sAct[prow * AR + tn * 16 + lrow] = (_Float16)softplus10(acc[r]);
            }
        }
    }
    __syncthreads();

    // ---- Layers 2 & 3: act @ w^T, K=64 ----
    const _Float16* sw = sW2;
#pragma unroll
    for (int layer = 0; layer < 2; ++layer) {
        h8 bw[2][4];
#pragma unroll
        for (int kh = 0; kh < 2; ++kh)
#pragma unroll
            for (int tn = 0; tn < 4; ++tn)
                bw[kh][tn] = *(const h8*)&sw[(lrow + 16 * tn) * W2R + kh * 32 + quad * 8];

#pragma unroll
        for (int t = 0; t < 4; ++t) {
            const int arow = (waveRow + t * 16 + lrow) * AR;
            h8 a0 = *(const h8*)&sAct[arow + quad * 8];
            h8 a1 = *(const h8*)&sAct[arow + 32 + quad * 8];
            f4 accs[4];
#pragma unroll
            for (int tn = 0; tn < 4; ++tn) {
                f4 acc = __builtin_amdgcn_mfma_f32_16x16x32_f16(a0, bw[0][tn], zero, 0, 0, 0);
                acc     = __builtin_amdgcn_mfma_f32_16x16x32_f16(a1, bw[1][tn], acc,  0, 0, 0);
                accs[tn] = acc;
            }
            // in-place: all reads of tile t's rows happened above (wave-ordered LDS)
#pragma unroll
            for (int tn = 0; tn < 4; ++tn)
#pragma unroll
                for (int r = 0; r < 4; ++r)
                    sAct[(waveRow + t * 16 + quad * 4 + r) * AR + tn * 16 + lrow] =
                        (_Float16)softplus10(accs[tn][r]);
        }
        sw = sW3;
        __syncthreads();
    }

    // ---- Layer 4: dot with w4 (each thread -> its own point/row) ----
    float sum = 0.f;
#pragma unroll
    for (int k8 = 0; k8 < 8; ++k8) {
        h8 a = *(const h8*)&sAct[tid * AR + k8 * 8];
#pragma unroll
        for (int j = 0; j < 8; ++j) sum += (float)a[j] * sW4[k8 * 8 + j];
    }
    out[blockPt + tid] = sum;
}

extern "C" void kernel_launch(void* const* d_in, const int* in_sizes, int n_in,
                              void* d_out, int out_size, void* d_ws, size_t ws_size,
                              hipStream_t stream) {
    const float* x     = (const float*)d_in[0];
    const float* table = (const float*)d_in[1];
    const float* w1    = (const float*)d_in[2];
    const float* w2    = (const float*)d_in[3];
    const float* w3    = (const float*)d_in[4];
    const float* w4    = (const float*)d_in[5];
    float* out = (float*)d_out;
    const int N = in_sizes[0] / 3;           // 1<<20
    _Float16* enc = (_Float16*)d_ws;         // N*32 f16 = 64 MB scratch

    Levels lv;
    lv.dense_mask = 0;
    const double pls = exp2(log2(2048.0 / 16.0) / 15.0);
    const double lg  = log2(pls);
    for (int l = 0; l < 16; ++l) {
        double sc = exp2((double)l * lg) * 16.0 - 1.0;
        int res = (int)ceil(sc) + 1;
        lv.scale[l] = (float)sc;
        lv.res[l]   = res;
        if ((long long)res * res * res <= (long long)T_SIZE) lv.dense_mask |= (1u << l);
    }

    const int blocks = (N + 255) / 256;
    hipLaunchKernelGGL(encode_kernel, dim3(blocks), dim3(256), 0, stream,
                       x, table, enc, lv, N);
    hipLaunchKernelGGL(mlp_kernel, dim3(N / 256), dim3(256), 0, stream,
                       enc, w1, w2, w3, w4, out);
}